// Round 1
// baseline (4997.021 us; speedup 1.0000x reference)
//
#include <hip/hip_runtime.h>
#include <hip/hip_bf16.h>
#include <math.h>

// Problem dims (fixed)
#define B   64
#define NN  196
#define HH  512
#define EE  512
#define AA  512
#define VV  20000
#define LL  20

// ---------------------------------------------------------------------------
// Generic tiled GEMM: C[M,N] = X[M,K] @ W[N,K]^T (+ bias[n]) (+= if accumulate)
// TILE 64x64, K-chunk 16, 256 threads, 4x4 microtile per thread.
// outMode==1: C index = (m&63)*400000 + ((m>>6)+1)*20000 + n   (logits layout)
// ---------------------------------------------------------------------------
#define TM 64
#define TN 64
#define TK 16

__global__ __launch_bounds__(256) void gemm_tiled(
    const float* __restrict__ X, const float* __restrict__ W,
    const float* __restrict__ bias, float* __restrict__ C,
    int M, int N, int K, int ldC, int accumulate, int outMode) {
  __shared__ float Xs[TK][TM + 4];
  __shared__ float Ws[TK][TN + 4];
  const int mBase = blockIdx.y * TM;
  const int nBase = blockIdx.x * TN;
  const int tid = threadIdx.x;
  const int tx = tid & 15;       // n microtile
  const int ty = tid >> 4;       // m microtile
  float acc[4][4] = {};

  for (int k0 = 0; k0 < K; k0 += TK) {
#pragma unroll
    for (int i = 0; i < 4; ++i) {
      int e = tid + i * 256;
      int r = e >> 4;
      int cc = e & 15;
      Xs[cc][r] = X[(size_t)(mBase + r) * K + k0 + cc];
      int n = nBase + r;
      Ws[cc][r] = (n < N) ? W[(size_t)n * K + k0 + cc] : 0.f;
    }
    __syncthreads();
#pragma unroll
    for (int kk = 0; kk < TK; ++kk) {
      float xv[4], wv[4];
#pragma unroll
      for (int i = 0; i < 4; ++i) xv[i] = Xs[kk][ty * 4 + i];
#pragma unroll
      for (int j = 0; j < 4; ++j) wv[j] = Ws[kk][tx * 4 + j];
#pragma unroll
      for (int i = 0; i < 4; ++i)
#pragma unroll
        for (int j = 0; j < 4; ++j) acc[i][j] += xv[i] * wv[j];
    }
    __syncthreads();
  }

#pragma unroll
  for (int i = 0; i < 4; ++i) {
    int m = mBase + ty * 4 + i;
#pragma unroll
    for (int j = 0; j < 4; ++j) {
      int n = nBase + tx * 4 + j;
      if (n < N) {
        float v = acc[i][j];
        if (bias) v += bias[n];
        size_t idx;
        if (outMode) {
          int bb = m & 63;
          int tt = m >> 6;
          idx = (size_t)bb * ((size_t)LL * VV) + (size_t)(tt + 1) * VV + n;
        } else {
          idx = (size_t)m * ldC + n;
        }
        if (accumulate) C[idx] += v; else C[idx] = v;
      }
    }
  }
}

// ---------------------------------------------------------------------------
// Attention scores: one wave per (b,n):
//   scores[b,n] = dot(tanh(enc_proj[b,n,:] + dec[b,:]), energy_W) + energy_b
// ---------------------------------------------------------------------------
__global__ __launch_bounds__(256) void attn_scores_kernel(
    const float* __restrict__ enc_proj, const float* __restrict__ dec,
    const float* __restrict__ eW, const float* __restrict__ eb,
    float* __restrict__ scores) {
  int wave = blockIdx.x * 4 + (threadIdx.x >> 6);
  int b = wave / NN, n = wave % NN;
  int lane = threadIdx.x & 63;
  const float* ep = enc_proj + ((size_t)b * NN + n) * AA;
  const float* dv = dec + (size_t)b * AA;
  float acc = 0.f;
#pragma unroll
  for (int j = 0; j < 8; ++j) {
    int idx = j * 64 + lane;
    acc += tanhf(ep[idx] + dv[idx]) * eW[idx];
  }
#pragma unroll
  for (int off = 32; off > 0; off >>= 1) acc += __shfl_down(acc, off, 64);
  if (lane == 0) scores[b * NN + n] = acc + eb[0];
}

// ---------------------------------------------------------------------------
// Softmax over N + context = attw @ enc_out[b] + embedding gather.
// Writes lstm_in[b] = [ emb[captions[b,t]] (512) | context (512) ]
// One block (256 thr) per b.
// ---------------------------------------------------------------------------
__global__ __launch_bounds__(256) void softmax_ctx_kernel(
    const float* __restrict__ scores, const float* __restrict__ enc_out,
    const float* __restrict__ emb, const int* __restrict__ captions, int t,
    float* __restrict__ lstm_in) {
  int b = blockIdx.x;
  int tid = threadIdx.x;
  __shared__ float sw[NN];
  __shared__ float red[256];

  float v = (tid < NN) ? scores[b * NN + tid] : -1e30f;
  red[tid] = v;
  __syncthreads();
  for (int s = 128; s > 0; s >>= 1) {
    if (tid < s) red[tid] = fmaxf(red[tid], red[tid + s]);
    __syncthreads();
  }
  float mx = red[0];
  __syncthreads();
  float e = (tid < NN) ? expf(v - mx) : 0.f;
  red[tid] = e;
  __syncthreads();
  for (int s = 128; s > 0; s >>= 1) {
    if (tid < s) red[tid] += red[tid + s];
    __syncthreads();
  }
  float inv = 1.f / red[0];
  if (tid < NN) sw[tid] = e * inv;
  __syncthreads();

  const float* eo = enc_out + (size_t)b * NN * HH;
  float acc0 = 0.f, acc1 = 0.f;
  for (int n = 0; n < NN; ++n) {
    float w = sw[n];
    acc0 += w * eo[(size_t)n * HH + tid];
    acc1 += w * eo[(size_t)n * HH + tid + 256];
  }
  float* li = lstm_in + (size_t)b * (EE + HH);
  li[EE + tid] = acc0;
  li[EE + tid + 256] = acc1;

  int cap = captions[b * LL + t];
  const float* er = emb + (size_t)cap * EE;
  li[tid] = er[tid];
  li[tid + 256] = er[tid + 256];
}

// ---------------------------------------------------------------------------
// LSTM pointwise: gates (B,4H) -> h_new (into h_hist slot t+1), c in place.
// ---------------------------------------------------------------------------
__global__ __launch_bounds__(256) void lstm_pointwise_kernel(
    const float* __restrict__ gates, float* __restrict__ h_out,
    float* __restrict__ c) {
  int idx = blockIdx.x * 256 + threadIdx.x;  // 0 .. 64*512
  int b = idx >> 9, j = idx & 511;
  const float* g = gates + (size_t)b * 2048;
  float ig = g[j], fg = g[512 + j], gg = g[1024 + j], og = g[1536 + j];
  float si = 1.f / (1.f + expf(-ig));
  float sf = 1.f / (1.f + expf(-fg));
  float so = 1.f / (1.f + expf(-og));
  float cn = sf * c[idx] + si * tanhf(gg);
  float hn = so * tanhf(cn);
  c[idx] = cn;
  h_out[idx] = hn;
}

// ---------------------------------------------------------------------------
// Zero out[:, 0, :]
// ---------------------------------------------------------------------------
__global__ __launch_bounds__(256) void zero_t0_kernel(float* __restrict__ out) {
  int idx = blockIdx.x * 256 + threadIdx.x;
  if (idx < B * VV) {
    int b = idx / VV, v = idx % VV;
    out[(size_t)b * ((size_t)LL * VV) + v] = 0.f;
  }
}

extern "C" void kernel_launch(void* const* d_in, const int* in_sizes, int n_in,
                              void* d_out, int out_size, void* d_ws, size_t ws_size,
                              hipStream_t stream) {
  const float* enc_out  = (const float*)d_in[0];
  const int*   captions = (const int*)d_in[1];
  const float* emb      = (const float*)d_in[2];
  const float* W_ih     = (const float*)d_in[3];
  const float* W_hh     = (const float*)d_in[4];
  const float* b_ih     = (const float*)d_in[5];
  const float* b_hh     = (const float*)d_in[6];
  const float* enc_W    = (const float*)d_in[7];
  const float* enc_b    = (const float*)d_in[8];
  const float* dec_W    = (const float*)d_in[9];
  const float* dec_b    = (const float*)d_in[10];
  const float* energy_W = (const float*)d_in[11];
  const float* energy_b = (const float*)d_in[12];
  const float* fc_W     = (const float*)d_in[13];
  const float* fc_b     = (const float*)d_in[14];
  float* out = (float*)d_out;

  // Workspace layout (floats)
  float* ws = (float*)d_ws;
  float* enc_proj = ws;                               // 12544*512 = 6,422,528
  float* h_hist   = enc_proj + (size_t)12544 * 512;   // 20 slots * 32768
  float* c        = h_hist + 20 * 32768;              // 32768
  float* dec      = c + 32768;                        // 32768
  float* scores   = dec + 32768;                      // 12544
  float* lstm_in  = scores + 12544;                   // 65536
  float* gates    = lstm_in + 65536;                  // 131072

  // h0 = 0 (h_hist slot 0), c0 = 0
  hipMemsetAsync(h_hist, 0, 32768 * sizeof(float), stream);
  hipMemsetAsync(c, 0, 32768 * sizeof(float), stream);
  zero_t0_kernel<<<(B * VV + 255) / 256, 256, 0, stream>>>(out);

  // enc_proj = enc_out @ enc_W^T + enc_b : M=12544, N=512, K=512
  gemm_tiled<<<dim3(AA / TN, (B * NN) / TM), 256, 0, stream>>>(
      enc_out, enc_W, enc_b, enc_proj, B * NN, AA, HH, AA, 0, 0);

  for (int t = 0; t < LL - 1; ++t) {
    const float* h_prev = h_hist + (size_t)t * 32768;
    float* h_new = h_hist + (size_t)(t + 1) * 32768;

    // dec = h_prev @ dec_W^T + dec_b : M=64, N=512, K=512
    gemm_tiled<<<dim3(AA / TN, 1), 256, 0, stream>>>(
        h_prev, dec_W, dec_b, dec, B, AA, HH, AA, 0, 0);

    // scores
    attn_scores_kernel<<<(B * NN) / 4, 256, 0, stream>>>(
        enc_proj, dec, energy_W, energy_b, scores);

    // softmax + context + embedding -> lstm_in
    softmax_ctx_kernel<<<B, 256, 0, stream>>>(
        scores, enc_out, emb, captions, t, lstm_in);

    // gates = lstm_in @ W_ih^T + b_ih : M=64, N=2048, K=1024
    gemm_tiled<<<dim3(2048 / TN, 1), 256, 0, stream>>>(
        lstm_in, W_ih, b_ih, gates, B, 4 * HH, EE + HH, 4 * HH, 0, 0);
    // gates += h_prev @ W_hh^T + b_hh : K=512
    gemm_tiled<<<dim3(2048 / TN, 1), 256, 0, stream>>>(
        h_prev, W_hh, b_hh, gates, B, 4 * HH, HH, 4 * HH, 1, 0);

    // pointwise LSTM -> h_new, c
    lstm_pointwise_kernel<<<(B * HH) / 256, 256, 0, stream>>>(gates, h_new, c);
  }

  // Batched logits: C[1216, 20000] = h_hist[1..19] @ fc_W^T + fc_b
  // rows m = t*64 + b, scattered into out[b, t+1, :]
  gemm_tiled<<<dim3((VV + TN - 1) / TN, (19 * B) / TM), 256, 0, stream>>>(
      h_hist + 32768, fc_W, fc_b, out, 19 * B, VV, HH, 0, 0, 1);
}

// Round 2
// 2300.689 us; speedup vs baseline: 2.1720x; 2.1720x over previous
//
#include <hip/hip_runtime.h>
#include <hip/hip_bf16.h>
#include <math.h>

// Problem dims (fixed)
#define B   64
#define NN  196
#define HH  512
#define EE  512
#define AA  512
#define VV  20000
#define LL  20

#define TM 64
#define TN 64
#define TK 16

__device__ __forceinline__ float tanh_fast(float x) {
  float e2 = __expf(2.f * x);
  return 1.f - 2.f / (e2 + 1.f);
}
__device__ __forceinline__ float sigmoid_fast(float x) {
  return 1.f / (1.f + __expf(-x));
}

// ---------------------------------------------------------------------------
// Generic tiled GEMM: C[M,N] = X[M,K] @ W[N,K]^T (+ bias[n])
// outMode==1: C index = (m&63)*400000 + ((m>>6)+1)*20000 + n (logits layout)
// ---------------------------------------------------------------------------
__global__ __launch_bounds__(256) void gemm_tiled(
    const float* __restrict__ X, const float* __restrict__ W,
    const float* __restrict__ bias, float* __restrict__ C,
    int M, int N, int K, int ldC, int outMode) {
  __shared__ float Xs[TK][TM + 4];
  __shared__ float Ws[TK][TN + 4];
  const int mBase = blockIdx.y * TM;
  const int nBase = blockIdx.x * TN;
  const int tid = threadIdx.x;
  const int tx = tid & 15;
  const int ty = tid >> 4;
  float acc[4][4] = {};

  for (int k0 = 0; k0 < K; k0 += TK) {
#pragma unroll
    for (int i = 0; i < 4; ++i) {
      int e = tid + i * 256;
      int r = e >> 4;
      int cc = e & 15;
      Xs[cc][r] = X[(size_t)(mBase + r) * K + k0 + cc];
      int n = nBase + r;
      Ws[cc][r] = (n < N) ? W[(size_t)n * K + k0 + cc] : 0.f;
    }
    __syncthreads();
#pragma unroll
    for (int kk = 0; kk < TK; ++kk) {
      float xv[4], wv[4];
#pragma unroll
      for (int i = 0; i < 4; ++i) xv[i] = Xs[kk][ty * 4 + i];
#pragma unroll
      for (int j = 0; j < 4; ++j) wv[j] = Ws[kk][tx * 4 + j];
#pragma unroll
      for (int i = 0; i < 4; ++i)
#pragma unroll
        for (int j = 0; j < 4; ++j) acc[i][j] += xv[i] * wv[j];
    }
    __syncthreads();
  }

#pragma unroll
  for (int i = 0; i < 4; ++i) {
    int m = mBase + ty * 4 + i;
#pragma unroll
    for (int j = 0; j < 4; ++j) {
      int n = nBase + tx * 4 + j;
      if (n < N) {
        float v = acc[i][j];
        if (bias) v += bias[n];
        size_t idx;
        if (outMode) {
          int bb = m & 63;
          int tt = m >> 6;
          idx = (size_t)bb * ((size_t)LL * VV) + (size_t)(tt + 1) * VV + n;
        } else {
          idx = (size_t)m * ldC + n;
        }
        C[idx] = v;
      }
    }
  }
}

// ---------------------------------------------------------------------------
// Skinny GEMM for M=64, split-K with atomic accumulation.
// Y[64,N] = X[64,K] @ W[N,K]^T
//   n <  splitN: atomicAdd into out0[m*2048 + n]            (gates)
//   n >= splitN: atomicAdd into out1[m*512 + n-splitN]      (dec), +bias1 on kz==0
// grid = (N/64, splitK); per-block K range = Ks = K/splitK
// ---------------------------------------------------------------------------
__global__ __launch_bounds__(256) void gemm_skinny(
    const float* __restrict__ X, const float* __restrict__ W,
    float* __restrict__ out0, float* __restrict__ out1,
    const float* __restrict__ bias1, int K, int Ks, int splitN) {
  __shared__ float Xs[TK][TM + 4];
  __shared__ float Ws[TK][TN + 4];
  const int nBase = blockIdx.x * TN;
  const int kBase = blockIdx.y * Ks;
  const int tid = threadIdx.x;
  const int tx = tid & 15;
  const int ty = tid >> 4;
  float acc[4][4] = {};

  for (int k0 = kBase; k0 < kBase + Ks; k0 += TK) {
#pragma unroll
    for (int i = 0; i < 4; ++i) {
      int e = tid + i * 256;
      int r = e >> 4;
      int cc = e & 15;
      Xs[cc][r] = X[(size_t)r * K + k0 + cc];
      Ws[cc][r] = W[(size_t)(nBase + r) * K + k0 + cc];
    }
    __syncthreads();
#pragma unroll
    for (int kk = 0; kk < TK; ++kk) {
      float xv[4], wv[4];
#pragma unroll
      for (int i = 0; i < 4; ++i) xv[i] = Xs[kk][ty * 4 + i];
#pragma unroll
      for (int j = 0; j < 4; ++j) wv[j] = Ws[kk][tx * 4 + j];
#pragma unroll
      for (int i = 0; i < 4; ++i)
#pragma unroll
        for (int j = 0; j < 4; ++j) acc[i][j] += xv[i] * wv[j];
    }
    __syncthreads();
  }

#pragma unroll
  for (int i = 0; i < 4; ++i) {
    int m = ty * 4 + i;
#pragma unroll
    for (int j = 0; j < 4; ++j) {
      int n = nBase + tx * 4 + j;
      float v = acc[i][j];
      if (n < splitN) {
        atomicAdd(&out0[(size_t)m * 2048 + n], v);
      } else {
        if (blockIdx.y == 0) v += bias1[n - splitN];
        atomicAdd(&out1[(size_t)m * 512 + (n - splitN)], v);
      }
    }
  }
}

// ---------------------------------------------------------------------------
// Build packed weights once per call:
//  Wb0[2048,512] = W_ih[:, 0:512]      (emb half)
//  Wb1[2560,512] = [W_hh ; dec_W]
//  Wb2[2048,512] = W_ih[:, 512:1024]   (context half)
//  bsum[2048]    = b_ih + b_hh
// ---------------------------------------------------------------------------
__global__ __launch_bounds__(256) void build_weights(
    const float* __restrict__ W_ih, const float* __restrict__ W_hh,
    const float* __restrict__ dec_W, const float* __restrict__ b_ih,
    const float* __restrict__ b_hh, float* __restrict__ Wb0,
    float* __restrict__ Wb1, float* __restrict__ Wb2,
    float* __restrict__ bsum) {
  int idx = blockIdx.x * 256 + threadIdx.x;
  if (idx < 2560 * 512) {
    int n = idx >> 9, k = idx & 511;
    Wb1[idx] = (n < 2048) ? W_hh[idx] : dec_W[(size_t)(n - 2048) * 512 + k];
  }
  if (idx < 2048 * 512) {
    int n = idx >> 9, k = idx & 511;
    Wb0[idx] = W_ih[(size_t)n * 1024 + k];
    Wb2[idx] = W_ih[(size_t)n * 1024 + 512 + k];
  }
  if (idx < 2048) bsum[idx] = b_ih[idx] + b_hh[idx];
}

// ---------------------------------------------------------------------------
// Gather embedding rows: embx[m=t*64+b, :] = emb[captions[b,t]]
// ---------------------------------------------------------------------------
__global__ __launch_bounds__(256) void gather_emb(
    const float* __restrict__ emb, const int* __restrict__ captions,
    float* __restrict__ embx) {
  int m = blockIdx.x;           // 0..1215
  int t = m >> 6, b = m & 63;
  int cap = captions[b * LL + t];
  int tid = threadIdx.x;
  embx[(size_t)m * 512 + tid] = emb[(size_t)cap * 512 + tid];
  embx[(size_t)m * 512 + 256 + tid] = emb[(size_t)cap * 512 + 256 + tid];
}

// ---------------------------------------------------------------------------
// Fused attention: per-b block (512 thr):
// scores = tanh(enc_proj + dec)·eW + eb ; softmax ; context = attw @ enc_out
// ---------------------------------------------------------------------------
__global__ __launch_bounds__(512) void attn_fused(
    const float* __restrict__ enc_proj, const float* __restrict__ enc_out,
    const float* __restrict__ dec, const float* __restrict__ eW,
    const float* __restrict__ eb, float* __restrict__ ctx) {
  int b = blockIdx.x;
  int tid = threadIdx.x;
  __shared__ float sdec[512];
  __shared__ float sw[NN];
  __shared__ float tmp[256];

  sdec[tid] = dec[b * 512 + tid];
  __syncthreads();

  int wave = tid >> 6, lane = tid & 63;
  float ew[8];
#pragma unroll
  for (int j = 0; j < 8; ++j) ew[j] = eW[j * 64 + lane];

  for (int n = wave; n < NN; n += 8) {
    const float* ep = enc_proj + ((size_t)b * NN + n) * 512;
    float acc = 0.f;
#pragma unroll
    for (int j = 0; j < 8; ++j) {
      float x = ep[j * 64 + lane] + sdec[j * 64 + lane];
      acc += tanh_fast(x) * ew[j];
    }
#pragma unroll
    for (int off = 32; off; off >>= 1) acc += __shfl_down(acc, off, 64);
    if (lane == 0) sw[n] = acc + eb[0];
  }
  __syncthreads();

  float v = (tid < NN) ? sw[tid] : -1e30f;
  if (tid < 256) tmp[tid] = v;
  __syncthreads();
  for (int s = 128; s; s >>= 1) {
    if (tid < s) tmp[tid] = fmaxf(tmp[tid], tmp[tid + s]);
    __syncthreads();
  }
  float mx = tmp[0];
  __syncthreads();
  float e = (tid < NN) ? __expf(v - mx) : 0.f;
  if (tid < 256) tmp[tid] = e;
  __syncthreads();
  for (int s = 128; s; s >>= 1) {
    if (tid < s) tmp[tid] += tmp[tid + s];
    __syncthreads();
  }
  float inv = 1.f / tmp[0];
  if (tid < NN) sw[tid] = e * inv;
  __syncthreads();

  const float* eo = enc_out + (size_t)b * NN * 512 + tid;
  float acc = 0.f;
#pragma unroll 4
  for (int n = 0; n < NN; ++n) acc += sw[n] * eo[(size_t)n * 512];
  ctx[b * 512 + tid] = acc;
}

// ---------------------------------------------------------------------------
// LSTM pointwise; also zeroes dec for the next step's split-K accumulation.
// ---------------------------------------------------------------------------
__global__ __launch_bounds__(256) void lstm_pointwise_kernel(
    const float* __restrict__ gates, float* __restrict__ h_out,
    float* __restrict__ c, float* __restrict__ dec) {
  int idx = blockIdx.x * 256 + threadIdx.x;  // 0 .. 64*512
  int b = idx >> 9, j = idx & 511;
  const float* g = gates + (size_t)b * 2048;
  float ig = g[j], fg = g[512 + j], gg = g[1024 + j], og = g[1536 + j];
  float si = sigmoid_fast(ig);
  float sf = sigmoid_fast(fg);
  float so = sigmoid_fast(og);
  float cn = sf * c[idx] + si * tanh_fast(gg);
  float hn = so * tanh_fast(cn);
  c[idx] = cn;
  h_out[idx] = hn;
  dec[idx] = 0.f;
}

__global__ __launch_bounds__(256) void zero_t0_kernel(float* __restrict__ out) {
  int idx = blockIdx.x * 256 + threadIdx.x;
  if (idx < B * VV) {
    int b = idx / VV, v = idx % VV;
    out[(size_t)b * ((size_t)LL * VV) + v] = 0.f;
  }
}

extern "C" void kernel_launch(void* const* d_in, const int* in_sizes, int n_in,
                              void* d_out, int out_size, void* d_ws, size_t ws_size,
                              hipStream_t stream) {
  const float* enc_out  = (const float*)d_in[0];
  const int*   captions = (const int*)d_in[1];
  const float* emb      = (const float*)d_in[2];
  const float* W_ih     = (const float*)d_in[3];
  const float* W_hh     = (const float*)d_in[4];
  const float* b_ih     = (const float*)d_in[5];
  const float* b_hh     = (const float*)d_in[6];
  const float* enc_W    = (const float*)d_in[7];
  const float* enc_b    = (const float*)d_in[8];
  const float* dec_W    = (const float*)d_in[9];
  const float* dec_b    = (const float*)d_in[10];
  const float* energy_W = (const float*)d_in[11];
  const float* energy_b = (const float*)d_in[12];
  const float* fc_W     = (const float*)d_in[13];
  const float* fc_b     = (const float*)d_in[14];
  float* out = (float*)d_out;

  // Workspace layout (floats)
  float* ws = (float*)d_ws;
  float* enc_proj = ws;                                // 12544*512
  float* h_hist   = enc_proj + (size_t)12544 * 512;    // 20 * 32768
  float* c        = h_hist + 20 * 32768;               // 32768
  float* dec      = c + 32768;                         // 32768
  float* ctx      = dec + 32768;                       // 32768
  float* gates_all= ctx + 32768;                       // 19 * 131072
  float* embx     = gates_all + 19 * 131072;           // 1216*512
  float* Wb0      = embx + 1216 * 512;                 // 2048*512
  float* Wb1      = Wb0 + 2048 * 512;                  // 2560*512
  float* Wb2      = Wb1 + 2560 * 512;                  // 2048*512
  float* bsum     = Wb2 + 2048 * 512;                  // 2048

  hipMemsetAsync(h_hist, 0, 32768 * sizeof(float), stream);
  hipMemsetAsync(c, 0, 32768 * sizeof(float), stream);
  hipMemsetAsync(dec, 0, 32768 * sizeof(float), stream);
  zero_t0_kernel<<<(B * VV + 255) / 256, 256, 0, stream>>>(out);

  // Pack weights
  build_weights<<<(2560 * 512) / 256, 256, 0, stream>>>(
      W_ih, W_hh, dec_W, b_ih, b_hh, Wb0, Wb1, Wb2, bsum);

  // Gather embeddings for all steps
  gather_emb<<<19 * B, 256, 0, stream>>>(emb, captions, embx);

  // Precompute emb half of gates for all steps:
  // gates_all[t*64+b, :] = embx @ Wb0^T + (b_ih + b_hh)
  gemm_tiled<<<dim3(2048 / TN, (19 * B) / TM), 256, 0, stream>>>(
      embx, Wb0, bsum, gates_all, 19 * B, 2048, 512, 2048, 0);

  // enc_proj = enc_out @ enc_W^T + enc_b
  gemm_tiled<<<dim3(AA / TN, (B * NN) / TM), 256, 0, stream>>>(
      enc_out, enc_W, enc_b, enc_proj, B * NN, AA, HH, AA, 0);

  for (int t = 0; t < LL - 1; ++t) {
    const float* h_prev = h_hist + (size_t)t * 32768;
    float* h_new = h_hist + (size_t)(t + 1) * 32768;
    float* gates_t = gates_all + (size_t)t * 131072;

    // [gates_hh | dec] = h_prev @ Wb1^T   (N=2560, K=512, splitK=4)
    gemm_skinny<<<dim3(2560 / TN, 4), 256, 0, stream>>>(
        h_prev, Wb1, gates_t, dec, dec_b, 512, 128, 2048);

    // fused attention -> ctx
    attn_fused<<<B, 512, 0, stream>>>(enc_proj, enc_out, dec, energy_W,
                                      energy_b, ctx);

    // gates += ctx @ Wb2^T  (N=2048, K=512, splitK=4)
    gemm_skinny<<<dim3(2048 / TN, 4), 256, 0, stream>>>(
        ctx, Wb2, gates_t, (float*)nullptr, (const float*)nullptr, 512, 128, 2048);

    // pointwise -> h_new, c; zero dec for next step
    lstm_pointwise_kernel<<<(B * HH) / 256, 256, 0, stream>>>(gates_t, h_new, c, dec);
  }

  // Batched logits: out[b, t+1, :] = h_hist[t+1][b] @ fc_W^T + fc_b
  gemm_tiled<<<dim3((VV + TN - 1) / TN, (19 * B) / TM), 256, 0, stream>>>(
      h_hist + 32768, fc_W, fc_b, out, 19 * B, VV, HH, 0, 1);
}

// Round 3
// 2084.019 us; speedup vs baseline: 2.3978x; 1.1040x over previous
//
#include <hip/hip_runtime.h>
#include <hip/hip_bf16.h>
#include <math.h>

// Problem dims (fixed)
#define B   64
#define NN  196
#define HH  512
#define EE  512
#define AA  512
#define VV  20000
#define LL  20

#define TM 64
#define TN 64
#define TK 16

typedef __attribute__((ext_vector_type(8))) short bf16x8;
typedef __attribute__((ext_vector_type(4))) float floatx4;

__device__ __forceinline__ float tanh_fast(float x) {
  float e2 = __expf(2.f * x);
  return 1.f - 2.f / (e2 + 1.f);
}
__device__ __forceinline__ float sigmoid_fast(float x) {
  return 1.f / (1.f + __expf(-x));
}

// ---------------------------------------------------------------------------
// bf16 MFMA GEMM: C[M,N] = Xb[M,K](bf16) @ Wb[N,K](bf16)^T + bias
// 128x128 tile, BK=32, 256 threads = 4 waves, each wave 64x64 via 16 MFMAs.
// Xb padded to M-tiles*128 rows, Wb padded to N-tiles*128 rows (zero fill).
// outMode==1: logits scatter out[b, t+1, n] with m = t*64 + b.
// ---------------------------------------------------------------------------
__global__ __launch_bounds__(256) void gemm_mfma_bt(
    const unsigned short* __restrict__ Xb, const unsigned short* __restrict__ Wb,
    const float* __restrict__ bias, float* __restrict__ C,
    int M, int N, int K, int ldC, int outMode) {
  __shared__ unsigned short As[128 * 32];
  __shared__ unsigned short Bs[128 * 32];
  const int tid = threadIdx.x;
  const int lane = tid & 63;
  const int l15 = lane & 15;
  const int q = lane >> 4;        // quad 0..3
  const int wv = tid >> 6;        // wave 0..3
  const int wm = (wv >> 1) * 64;  // wave m-offset in tile
  const int wn = (wv & 1) * 64;   // wave n-offset in tile
  const int mBase = blockIdx.y * 128;
  const int nBase = blockIdx.x * 128;

  // staging: tile = 512 chunks of 16B; each thread stages chunks tid, tid+256
  const int c0 = tid, c1 = tid + 256;
  const int r0 = c0 >> 2, o0 = (c0 & 3) * 8;
  const int r1 = c1 >> 2, o1 = (c1 & 3) * 8;

  floatx4 zero = {0.f, 0.f, 0.f, 0.f};
  floatx4 acc[4][4];
#pragma unroll
  for (int i = 0; i < 4; ++i)
#pragma unroll
    for (int j = 0; j < 4; ++j) acc[i][j] = zero;

  for (int k0 = 0; k0 < K; k0 += 32) {
    uint4 a0 = *(const uint4*)(Xb + (size_t)(mBase + r0) * K + k0 + o0);
    uint4 a1 = *(const uint4*)(Xb + (size_t)(mBase + r1) * K + k0 + o1);
    uint4 b0 = *(const uint4*)(Wb + (size_t)(nBase + r0) * K + k0 + o0);
    uint4 b1 = *(const uint4*)(Wb + (size_t)(nBase + r1) * K + k0 + o1);
    __syncthreads();
    *(uint4*)&As[c0 * 8] = a0;
    *(uint4*)&As[c1 * 8] = a1;
    *(uint4*)&Bs[c0 * 8] = b0;
    *(uint4*)&Bs[c1 * 8] = b1;
    __syncthreads();
    bf16x8 af[4], bfv[4];
#pragma unroll
    for (int i = 0; i < 4; ++i)
      af[i] = *(const bf16x8*)&As[(wm + i * 16 + l15) * 32 + q * 8];
#pragma unroll
    for (int j = 0; j < 4; ++j)
      bfv[j] = *(const bf16x8*)&Bs[(wn + j * 16 + l15) * 32 + q * 8];
#pragma unroll
    for (int i = 0; i < 4; ++i)
#pragma unroll
      for (int j = 0; j < 4; ++j)
        acc[i][j] = __builtin_amdgcn_mfma_f32_16x16x32_bf16(af[i], bfv[j],
                                                            acc[i][j], 0, 0, 0);
  }

  // Epilogue: C/D layout col = lane&15, row = quad*4 + reg  [m89/m91 verified]
#pragma unroll
  for (int i = 0; i < 4; ++i) {
#pragma unroll
    for (int j = 0; j < 4; ++j) {
#pragma unroll
      for (int p = 0; p < 4; ++p) {
        int m = mBase + wm + i * 16 + q * 4 + p;
        int n = nBase + wn + j * 16 + l15;
        if (m < M && n < N) {
          float v = acc[i][j][p];
          if (bias) v += bias[n];
          size_t idx;
          if (outMode) {
            idx = (size_t)(m & 63) * ((size_t)LL * VV) +
                  (size_t)((m >> 6) + 1) * VV + n;
          } else {
            idx = (size_t)m * ldC + n;
          }
          C[idx] = v;
        }
      }
    }
  }
}

// ---------------------------------------------------------------------------
// fp32 -> bf16 conversion with optional row padding (zero fill) and stride.
// dst[r*512 + c] = r < srcRows ? bf16(src[r*srcStride + colOff + c]) : 0
// ---------------------------------------------------------------------------
__global__ __launch_bounds__(256) void convert_pad(
    const float* __restrict__ src, unsigned short* __restrict__ dst,
    int srcRows, int dstRows, int srcStride, int colOff) {
  int idx = blockIdx.x * 256 + threadIdx.x;
  if (idx >= dstRows * 512) return;
  int r = idx >> 9, cc = idx & 511;
  float v = (r < srcRows) ? src[(size_t)r * srcStride + colOff + cc] : 0.f;
  __hip_bfloat16 h = __float2bfloat16(v);
  dst[idx] = *reinterpret_cast<unsigned short*>(&h);
}

// ---------------------------------------------------------------------------
// Skinny GEMM, M=64, split-K, atomic accumulate into out[m*2048+n].
// X[64,K] fp32, W[N,K] fp32. grid = (N/64, splitK), per-block K range Ks.
// ---------------------------------------------------------------------------
__global__ __launch_bounds__(256) void gemm_skinny(
    const float* __restrict__ X, const float* __restrict__ W,
    float* __restrict__ out, int K, int Ks) {
  __shared__ float Xs[TK][TM + 4];
  __shared__ float Ws[TK][TN + 4];
  const int nBase = blockIdx.x * TN;
  const int kBase = blockIdx.y * Ks;
  const int tid = threadIdx.x;
  const int tx = tid & 15;
  const int ty = tid >> 4;
  float acc[4][4] = {};

  for (int k0 = kBase; k0 < kBase + Ks; k0 += TK) {
#pragma unroll
    for (int i = 0; i < 4; ++i) {
      int e = tid + i * 256;
      int r = e >> 4;
      int cc = e & 15;
      Xs[cc][r] = X[(size_t)r * K + k0 + cc];
      Ws[cc][r] = W[(size_t)(nBase + r) * K + k0 + cc];
    }
    __syncthreads();
#pragma unroll
    for (int kk = 0; kk < TK; ++kk) {
      float xv[4], wvv[4];
#pragma unroll
      for (int i = 0; i < 4; ++i) xv[i] = Xs[kk][ty * 4 + i];
#pragma unroll
      for (int j = 0; j < 4; ++j) wvv[j] = Ws[kk][tx * 4 + j];
#pragma unroll
      for (int i = 0; i < 4; ++i)
#pragma unroll
        for (int j = 0; j < 4; ++j) acc[i][j] += xv[i] * wvv[j];
    }
    __syncthreads();
  }

#pragma unroll
  for (int i = 0; i < 4; ++i) {
    int m = ty * 4 + i;
#pragma unroll
    for (int j = 0; j < 4; ++j) {
      int n = nBase + tx * 4 + j;
      atomicAdd(&out[(size_t)m * 2048 + n], acc[i][j]);
    }
  }
}

// ---------------------------------------------------------------------------
// Pack weights once per call:
//  Wb3[2048][1024] = [W_hh | W_ih[:,512:1024]]   (for xcat=[h|ctx] GEMM)
//  dec_Wt[512][512] = dec_W^T                     (k-major for coalesced attn)
//  bsum[2048] = b_ih + b_hh
// ---------------------------------------------------------------------------
__global__ __launch_bounds__(256) void build_weights(
    const float* __restrict__ W_ih, const float* __restrict__ W_hh,
    const float* __restrict__ dec_W, const float* __restrict__ b_ih,
    const float* __restrict__ b_hh, float* __restrict__ Wb3,
    float* __restrict__ dec_Wt, float* __restrict__ bsum) {
  int idx = blockIdx.x * 256 + threadIdx.x;
  if (idx < 2048 * 1024) {
    int n = idx >> 10, k = idx & 1023;
    Wb3[idx] = (k < 512) ? W_hh[(size_t)n * 512 + k]
                         : W_ih[(size_t)n * 1024 + 512 + (k - 512)];
  }
  if (idx < 512 * 512) {
    int k = idx >> 9, j = idx & 511;
    dec_Wt[idx] = dec_W[(size_t)j * 512 + k];
  }
  if (idx < 2048) bsum[idx] = b_ih[idx] + b_hh[idx];
}

// ---------------------------------------------------------------------------
// Gather embeddings -> bf16, rows m = t*64+b, zero pad rows 1216..1279
// ---------------------------------------------------------------------------
__global__ __launch_bounds__(256) void gather_emb(
    const float* __restrict__ emb, const int* __restrict__ captions,
    unsigned short* __restrict__ embx) {
  int m = blockIdx.x;
  int tid = threadIdx.x;
  if (m >= 1216) {
    embx[(size_t)m * 512 + tid] = 0;
    embx[(size_t)m * 512 + 256 + tid] = 0;
    return;
  }
  int t = m >> 6, b = m & 63;
  int cap = captions[b * LL + t];
#pragma unroll
  for (int i = 0; i < 2; ++i) {
    float v = emb[(size_t)cap * 512 + i * 256 + tid];
    __hip_bfloat16 h = __float2bfloat16(v);
    embx[(size_t)m * 512 + i * 256 + tid] = *reinterpret_cast<unsigned short*>(&h);
  }
}

// ---------------------------------------------------------------------------
// Fused per-step attention (one block of 512 thr per b):
//   dec = h @ dec_W^T + dec_b          (h read from xcat[:, 0:512])
//   scores = tanh(enc_proj + dec) . eW + eb ; softmax over N
//   ctx = attw @ enc_out  -> xcat[:, 512:1024]
// ---------------------------------------------------------------------------
__global__ __launch_bounds__(512) void attn_dec(
    const float* __restrict__ enc_proj, const float* __restrict__ enc_out,
    const float* __restrict__ dec_Wt, const float* __restrict__ dec_b,
    const float* __restrict__ eW, const float* __restrict__ eb,
    float* __restrict__ xcat) {
  int b = blockIdx.x;
  int tid = threadIdx.x;
  __shared__ float hs[512];
  __shared__ float sdec[512];
  __shared__ float sw[NN];
  __shared__ float tmp[256];

  hs[tid] = xcat[(size_t)b * 1024 + tid];
  __syncthreads();

  // dec[tid] = sum_k hs[k] * dec_Wt[k][tid] + dec_b[tid]
  float dacc = dec_b[tid];
#pragma unroll 8
  for (int k = 0; k < 512; ++k) dacc += hs[k] * dec_Wt[(size_t)k * 512 + tid];
  sdec[tid] = dacc;
  __syncthreads();

  int wvv = tid >> 6, lane = tid & 63;
  float ew[8], sd[8];
#pragma unroll
  for (int j = 0; j < 8; ++j) {
    ew[j] = eW[j * 64 + lane];
    sd[j] = sdec[j * 64 + lane];
  }

  for (int n = wvv; n < NN; n += 8) {
    const float* ep = enc_proj + ((size_t)b * NN + n) * 512;
    float a = 0.f;
#pragma unroll
    for (int j = 0; j < 8; ++j) a += tanh_fast(ep[j * 64 + lane] + sd[j]) * ew[j];
#pragma unroll
    for (int off = 32; off; off >>= 1) a += __shfl_down(a, off, 64);
    if (lane == 0) sw[n] = a + eb[0];
  }
  __syncthreads();

  float v = (tid < NN) ? sw[tid] : -1e30f;
  if (tid < 256) tmp[tid] = v;
  __syncthreads();
  for (int s = 128; s; s >>= 1) {
    if (tid < s) tmp[tid] = fmaxf(tmp[tid], tmp[tid + s]);
    __syncthreads();
  }
  float mx = tmp[0];
  __syncthreads();
  float e = (tid < NN) ? __expf(v - mx) : 0.f;
  if (tid < 256) tmp[tid] = e;
  __syncthreads();
  for (int s = 128; s; s >>= 1) {
    if (tid < s) tmp[tid] += tmp[tid + s];
    __syncthreads();
  }
  float inv = 1.f / tmp[0];
  if (tid < NN) sw[tid] = e * inv;
  __syncthreads();

  const float* eo = enc_out + (size_t)b * NN * 512 + tid;
  float a = 0.f;
#pragma unroll 4
  for (int n = 0; n < NN; ++n) a += sw[n] * eo[(size_t)n * 512];
  xcat[(size_t)b * 1024 + 512 + tid] = a;
}

// ---------------------------------------------------------------------------
// LSTM pointwise: gates -> h (into h_hist slot and xcat[:,0:512]), c in place
// ---------------------------------------------------------------------------
__global__ __launch_bounds__(256) void lstm_pointwise_kernel(
    const float* __restrict__ gates, float* __restrict__ h_out,
    float* __restrict__ c, float* __restrict__ xcat) {
  int idx = blockIdx.x * 256 + threadIdx.x;  // 0 .. 64*512
  int b = idx >> 9, j = idx & 511;
  const float* g = gates + (size_t)b * 2048;
  float ig = g[j], fg = g[512 + j], gg = g[1024 + j], og = g[1536 + j];
  float si = sigmoid_fast(ig);
  float sf = sigmoid_fast(fg);
  float so = sigmoid_fast(og);
  float cn = sf * c[idx] + si * tanh_fast(gg);
  float hn = so * tanh_fast(cn);
  c[idx] = cn;
  h_out[idx] = hn;
  xcat[(size_t)b * 1024 + j] = hn;
}

__global__ __launch_bounds__(256) void zero_t0_kernel(float* __restrict__ out) {
  int idx = blockIdx.x * 256 + threadIdx.x;
  if (idx < B * VV) {
    int b = idx / VV, v = idx % VV;
    out[(size_t)b * ((size_t)LL * VV) + v] = 0.f;
  }
}

extern "C" void kernel_launch(void* const* d_in, const int* in_sizes, int n_in,
                              void* d_out, int out_size, void* d_ws, size_t ws_size,
                              hipStream_t stream) {
  const float* enc_out  = (const float*)d_in[0];
  const int*   captions = (const int*)d_in[1];
  const float* emb      = (const float*)d_in[2];
  const float* W_ih     = (const float*)d_in[3];
  const float* W_hh     = (const float*)d_in[4];
  const float* b_ih     = (const float*)d_in[5];
  const float* b_hh     = (const float*)d_in[6];
  const float* enc_W    = (const float*)d_in[7];
  const float* enc_b    = (const float*)d_in[8];
  const float* dec_W    = (const float*)d_in[9];
  const float* dec_b    = (const float*)d_in[10];
  const float* energy_W = (const float*)d_in[11];
  const float* energy_b = (const float*)d_in[12];
  const float* fc_W     = (const float*)d_in[13];
  const float* fc_b     = (const float*)d_in[14];
  float* out = (float*)d_out;

  // Workspace layout
  float* ws = (float*)d_ws;
  float* enc_proj  = ws;                                 // 12544*512
  float* h_hist    = enc_proj + (size_t)12544 * 512;     // 20 * 32768
  float* c         = h_hist + 20 * 32768;                // 32768
  float* xcat      = c + 32768;                          // 64*1024
  float* gates_all = xcat + 65536;                       // 19 * 131072
  float* Wb3       = gates_all + 19 * 131072;            // 2048*1024
  float* dec_Wt    = Wb3 + 2048 * 1024;                  // 512*512
  float* bsum      = dec_Wt + 262144;                    // 2048
  unsigned short* fcWb    = (unsigned short*)(bsum + 2048); // 20096*512
  unsigned short* encWb   = fcWb + (size_t)20096 * 512;     // 512*512
  unsigned short* encOutb = encWb + (size_t)512 * 512;      // 12544*512
  unsigned short* Wb0b    = encOutb + (size_t)12544 * 512;  // 2048*512
  unsigned short* embxb   = Wb0b + (size_t)2048 * 512;      // 1280*512
  unsigned short* hb      = embxb + (size_t)1280 * 512;     // 1280*512

  hipMemsetAsync(xcat, 0, 65536 * sizeof(float), stream);
  hipMemsetAsync(c, 0, 32768 * sizeof(float), stream);
  zero_t0_kernel<<<(B * VV + 255) / 256, 256, 0, stream>>>(out);

  // Pack fp32 weights for recurrent path
  build_weights<<<(2048 * 1024) / 256, 256, 0, stream>>>(
      W_ih, W_hh, dec_W, b_ih, b_hh, Wb3, dec_Wt, bsum);

  // bf16 conversions for MFMA operands
  convert_pad<<<(20096 * 512) / 256, 256, 0, stream>>>(fc_W, fcWb, 20000, 20096, 512, 0);
  convert_pad<<<(512 * 512) / 256, 256, 0, stream>>>(enc_W, encWb, 512, 512, 512, 0);
  convert_pad<<<(12544 * 512) / 256, 256, 0, stream>>>(enc_out, encOutb, 12544, 12544, 512, 0);
  convert_pad<<<(2048 * 512) / 256, 256, 0, stream>>>(W_ih, Wb0b, 2048, 2048, 1024, 0);

  gather_emb<<<1280, 256, 0, stream>>>(emb, captions, embxb);

  // gates_all[t*64+b, :] = embx @ W_ih[:, :512]^T + (b_ih + b_hh)   [MFMA]
  gemm_mfma_bt<<<dim3(16, 10), 256, 0, stream>>>(
      embxb, Wb0b, bsum, gates_all, 1216, 2048, 512, 2048, 0);

  // enc_proj = enc_out @ enc_W^T + enc_b   [MFMA]
  gemm_mfma_bt<<<dim3(4, 98), 256, 0, stream>>>(
      encOutb, encWb, enc_b, enc_proj, 12544, 512, 512, 512, 0);

  for (int t = 0; t < LL - 1; ++t) {
    float* h_new = h_hist + (size_t)(t + 1) * 32768;
    float* gates_t = gates_all + (size_t)t * 131072;

    // dec + attention + context (reads xcat h, writes xcat ctx)
    attn_dec<<<B, 512, 0, stream>>>(enc_proj, enc_out, dec_Wt, dec_b,
                                    energy_W, energy_b, xcat);

    // gates += [h|ctx] @ [W_hh | W_ih_ctx]^T  (K=1024, splitK=8 -> 256 blocks)
    gemm_skinny<<<dim3(2048 / TN, 8), 256, 0, stream>>>(xcat, Wb3, gates_t,
                                                        1024, 128);

    // pointwise -> h_new (h_hist + xcat), c
    lstm_pointwise_kernel<<<(B * HH) / 256, 256, 0, stream>>>(gates_t, h_new, c,
                                                              xcat);
  }

  // h_hist slots 1..19 -> bf16 (pad to 1280 rows)
  convert_pad<<<(1280 * 512) / 256, 256, 0, stream>>>(h_hist + 32768, hb, 1216,
                                                      1280, 512, 0);

  // Batched logits: out[b, t+1, :] = h @ fc_W^T + fc_b   [MFMA, scatter]
  gemm_mfma_bt<<<dim3(157, 10), 256, 0, stream>>>(
      hb, fcWb, fc_b, out, 1216, 20000, 512, 0, 1);
}